// Round 14
// baseline (354.005 us; speedup 1.0000x reference)
//
#include <hip/hip_runtime.h>
#include <math.h>

// Problem dims (fixed by reference setup_inputs)
#define BH 8        // heads
#define KK 512      // clusters
#define DD 64       // dim
#define NT 16384    // tokens per head = b*n = 4*4096
#define IDS_N (NT*BH)   // 131072 cluster-id outputs
#define CH 128      // clusters staged in LDS per chunk
#define TPB 256     // threads per assign block
#define TOK 4       // tokens per thread (amortizes broadcast ds_read)
#define KSPLIT 2    // codebook halves (grid z)
#define KH (KK/KSPLIT)  // 256 clusters per block

// ws layout (u32 words):
//   [0,      4096)           g_hist
//   [4096,   8192)           cursor
//   [8192,   8192+131072)    tokbuf
//   [139264, +524288)        part — float2 (dist, idx) per (split, head, token)

// ---------------------------------------------------------------------------
// Kernel 1: partial argmin over one codebook half. T=4 tokens/thread halves
// the ds_read count vs r13 (LDS-return-BW model: 12 cyc per broadcast
// ds_read_b128, validated r8/r13). Codebook half split over blockIdx.z keeps
// grid at 256 blocks. Math order identical to absmax=0 kernels.
// grid = (NT/1024, BH, 2), block = 256.
// ---------------------------------------------------------------------------
__global__ __launch_bounds__(TPB) void vq_assign(
    const float* __restrict__ x,       // [NT, BH*DD]
    const float* __restrict__ means,   // [BH, KK, DD]
    float2* __restrict__ part)         // [KSPLIT, BH, NT] (dist, idx)
{
    const int h   = blockIdx.y;
    const int s   = blockIdx.z;
    const int tid = threadIdx.x;
    const int tb  = blockIdx.x * (TPB * TOK);

    __shared__ float4 s_mrow[CH * (DD / 4)];  // 32 KB codebook chunk
    __shared__ float  s_m2[KH];               // 1 KB

    const float4* __restrict__ mh =
        (const float4*)(means + ((size_t)h * KK + s * KH) * DD);

    // |m|^2 for this half's 256 clusters
    for (int r = tid; r < KH; r += TPB) {
        const float4* row = mh + r * (DD / 4);
        float a0 = 0.f, a1 = 0.f, a2 = 0.f, a3 = 0.f;
#pragma unroll
        for (int j = 0; j < DD / 4; ++j) {
            float4 m = row[j];
            a0 = fmaf(m.x, m.x, a0);
            a1 = fmaf(m.y, m.y, a1);
            a2 = fmaf(m.z, m.z, a2);
            a3 = fmaf(m.w, m.w, a3);
        }
        s_m2[r] = (a0 + a1) + (a2 + a3);
    }

    // Four tokens' x into registers, pre-scaled by -2 (exact pow2).
    float4 xv[TOK][16];
#pragma unroll
    for (int tok = 0; tok < TOK; ++tok) {
        const float4* g =
            (const float4*)(x + (size_t)(tb + tok * TPB + tid) * (BH * DD) + h * DD);
#pragma unroll
        for (int j = 0; j < 16; ++j) {
            float4 v = g[j];
            xv[tok][j] = make_float4(-2.f * v.x, -2.f * v.y, -2.f * v.z, -2.f * v.w);
        }
    }

    float best[TOK];
    int   bid[TOK];
#pragma unroll
    for (int tok = 0; tok < TOK; ++tok) { best[tok] = 3.4e38f; bid[tok] = 0; }

    for (int c = 0; c < KH / CH; ++c) {       // 2 chunks of 128 rows
        __syncthreads();
        const float4* src = mh + c * CH * (DD / 4);
        for (int j = tid; j < CH * (DD / 4); j += TPB) s_mrow[j] = src[j];
        __syncthreads();

        const int kbase = s * KH + c * CH;
        for (int kk = 0; kk < CH; ++kk) {
            const float4* row = &s_mrow[kk * (DD / 4)];  // broadcast read
            const float m2k = s_m2[c * CH + kk];
            float acc[TOK][4];
#pragma unroll
            for (int tok = 0; tok < TOK; ++tok) {
                acc[tok][0] = m2k; acc[tok][1] = 0.f;
                acc[tok][2] = 0.f; acc[tok][3] = 0.f;
            }
#pragma unroll
            for (int j = 0; j < 16; ++j) {
                float4 m = row[j];              // one ds_read, four tokens
#pragma unroll
                for (int tok = 0; tok < TOK; ++tok) {
                    acc[tok][0] = fmaf(xv[tok][j].x, m.x, acc[tok][0]);
                    acc[tok][1] = fmaf(xv[tok][j].y, m.y, acc[tok][1]);
                    acc[tok][2] = fmaf(xv[tok][j].z, m.z, acc[tok][2]);
                    acc[tok][3] = fmaf(xv[tok][j].w, m.w, acc[tok][3]);
                }
            }
            const int k = kbase + kk;
#pragma unroll
            for (int tok = 0; tok < TOK; ++tok) {
                float d = (acc[tok][0] + acc[tok][1]) + (acc[tok][2] + acc[tok][3]);
                if (d < best[tok]) { best[tok] = d; bid[tok] = k; }  // strict <
            }
        }
    }

    float2* pp = part + ((size_t)s * BH + h) * NT;
#pragma unroll
    for (int tok = 0; tok < TOK; ++tok)
        pp[tb + tok * TPB + tid] = make_float2(best[tok], (float)bid[tok]);
}

// ---------------------------------------------------------------------------
// Kernel 1b: combine the two halves' partials -> ids + histogram.
// Tie (d0 == d1 impossible to favor wrong side: pick half-1 only if strictly
// smaller -> half-0 wins ties = lower cluster index = jnp.argmin rule).
// grid = (NT/256, BH), block = 256.
// ---------------------------------------------------------------------------
__global__ __launch_bounds__(256) void vq_combine(
    const float2* __restrict__ part,
    float* __restrict__ out_ids,
    unsigned int* __restrict__ g_hist)
{
    const int h   = blockIdx.y;
    const int tid = threadIdx.x;
    const int t   = blockIdx.x * 256 + tid;

    __shared__ unsigned int s_hist[KK];
    for (int r = tid; r < KK; r += 256) s_hist[r] = 0u;
    __syncthreads();

    float2 p0 = part[((size_t)0 * BH + h) * NT + t];
    float2 p1 = part[((size_t)1 * BH + h) * NT + t];
    int bi = (p1.x < p0.x) ? (int)p1.y : (int)p0.y;

    out_ids[(size_t)t * BH + h] = (float)bi;   // [b,n,h] layout
    atomicAdd(&s_hist[bi], 1u);
    __syncthreads();
    for (int r = tid; r < KK; r += 256) {
        unsigned int v = s_hist[r];
        if (v) atomicAdd(&g_hist[h * KK + r], v);
    }
}

// ---------------------------------------------------------------------------
// Kernel 2: per-head exclusive prefix sum of counts -> cursor.
// ---------------------------------------------------------------------------
__global__ __launch_bounds__(512) void vq_scan(
    const unsigned int* __restrict__ g_hist,
    unsigned int* __restrict__ cursor)
{
    const int h = blockIdx.x;
    const int tid = threadIdx.x;
    __shared__ unsigned int s[KK];

    unsigned int own = g_hist[h * KK + tid];
    s[tid] = own;
    __syncthreads();
    for (int off = 1; off < KK; off <<= 1) {
        unsigned int v = 0;
        if (tid >= off) v = s[tid - off];
        __syncthreads();
        s[tid] += v;
        __syncthreads();
    }
    cursor[h * KK + tid] = s[tid] - own;   // exclusive
}

// ---------------------------------------------------------------------------
// Kernel 3: scatter token indices into buckets. One cursor atomic per token.
// ---------------------------------------------------------------------------
__global__ __launch_bounds__(256) void vq_scatter(
    const float* __restrict__ out_ids,
    unsigned int* __restrict__ cursor,
    unsigned int* __restrict__ tokbuf)   // [BH*NT]
{
    const int h = blockIdx.y;
    const int t = blockIdx.x * 256 + threadIdx.x;
    int id = (int)out_ids[(size_t)t * BH + h];
    unsigned int slot = atomicAdd(&cursor[h * KK + id], 1u);
    tokbuf[(size_t)h * NT + slot] = (unsigned int)t;
}

// ---------------------------------------------------------------------------
// Kernel 4: one BLOCK (4 waves) per (h,k) bucket, 16 parallel load chains.
// lane = dim. Zero atomics, fused EMA. grid = BH*KK blocks of 256.
// ---------------------------------------------------------------------------
__global__ __launch_bounds__(256) void vq_gather(
    const float* __restrict__ x,
    const float* __restrict__ means,
    const unsigned int* __restrict__ g_hist,
    const unsigned int* __restrict__ cursor,   // now offset+count
    const unsigned int* __restrict__ tokbuf,
    float* __restrict__ out_means)
{
    const int w    = blockIdx.x;            // bucket id (h*KK+k)
    const int wid  = threadIdx.x >> 6;      // wave 0..3
    const int lane = threadIdx.x & 63;
    const int h    = w >> 9;

    const unsigned int cnt = g_hist[w];
    const unsigned int off = cursor[w] - cnt;
    const unsigned int* tb = tokbuf + (size_t)h * NT + off;
    const float* xb = x + h * DD + lane;

    float a0 = 0.f, a1 = 0.f, a2 = 0.f, a3 = 0.f;
    unsigned int i = wid;
    for (; i + 12 < cnt; i += 16) {          // 4 independent loads in flight
        unsigned int t0 = tb[i], t1 = tb[i + 4], t2 = tb[i + 8], t3 = tb[i + 12];
        a0 += xb[(size_t)t0 * (BH * DD)];
        a1 += xb[(size_t)t1 * (BH * DD)];
        a2 += xb[(size_t)t2 * (BH * DD)];
        a3 += xb[(size_t)t3 * (BH * DD)];
    }
    for (; i < cnt; i += 4)
        a0 += xb[(size_t)tb[i] * (BH * DD)];

    __shared__ float sp[4][DD];
    sp[wid][lane] = (a0 + a1) + (a2 + a3);
    __syncthreads();
    if (wid == 0) {
        float s = (sp[0][lane] + sp[1][lane]) + (sp[2][lane] + sp[3][lane]);
        float nm = s / (1e-6f + (float)cnt);
        float m  = means[(size_t)w * DD + lane];
        out_means[(size_t)w * DD + lane] = 0.001f * nm + 0.999f * m;
    }
}

extern "C" void kernel_launch(void* const* d_in, const int* in_sizes, int n_in,
                              void* d_out, int out_size, void* d_ws, size_t ws_size,
                              hipStream_t stream) {
    const float* x     = (const float*)d_in[0];   // [4,4096,512] f32
    const float* means = (const float*)d_in[1];   // [8,512,64]  f32

    float* out       = (float*)d_out;
    float* out_ids   = out;            // first 131072 floats
    float* out_means = out + IDS_N;    // next 262144 floats

    unsigned int* g_hist = (unsigned int*)d_ws;          // 4096
    unsigned int* cursor = g_hist + BH * KK;             // 4096
    unsigned int* tokbuf = cursor + BH * KK;             // 131072
    float2*       part   = (float2*)(tokbuf + IDS_N);    // 2*BH*NT float2 (2 MB)

    hipMemsetAsync(g_hist, 0, BH * KK * sizeof(unsigned int), stream);

    dim3 agrid(NT / (TPB * TOK), BH, KSPLIT);
    vq_assign <<<agrid, dim3(TPB), 0, stream>>>(x, means, part);
    dim3 cgrid(NT / 256, BH);
    vq_combine<<<cgrid, dim3(256), 0, stream>>>(part, out_ids, g_hist);
    vq_scan   <<<BH, dim3(512), 0, stream>>>(g_hist, cursor);
    vq_scatter<<<cgrid, dim3(256), 0, stream>>>(out_ids, cursor, tokbuf);
    vq_gather <<<BH * KK, dim3(256), 0, stream>>>(
        x, means, g_hist, cursor, tokbuf, out_means);
}